// Round 5
// baseline (50783.304 us; speedup 1.0000x reference)
//
#include <hip/hip_runtime.h>
#include <math.h>

// Problem constants
#define BB 16
#define TT 128
#define F_IN 240
#define E_DIM 1024
#define HH 320
#define G4 1280        // 4*H
#define JHD 512
#define VV 29
#define BLANKV 28
#define MAXSYM 3
#define LBUF (TT*MAXSYM) // 384

#define NB 16          // persistent grid blocks
#define HPITCH 328     // padded LDS row pitch (floats), 16B aligned
#define HP4 (HPITCH/4)

// Workspace layout (float offsets)
#define OFF_FPROJ 0ul                        // 2048*512 = 1048576
#define OFF_WJHR  1048576ul                  // 512*320 row-major (j,k)
#define OFF_EP    (OFF_WJHR + 163840ul)      // 29*1280
#define OFF_B1    (OFF_EP + 37120ul)         // 1280
#define OFF_H0P   (OFF_B1 + 1280ul)          // 16*320 pending h0
#define OFF_H1P   (OFF_H0P + 5120ul)         // 16*320 pending h1
#define OFF_PLOG  (OFF_H1P + 5120ul)         // 16*464
#define OFF_SYNC  (OFF_PLOG + 7424ul)        // 128 ints

typedef float f32x4 __attribute__((ext_vector_type(4)));
typedef unsigned u32x4 __attribute__((ext_vector_type(4)));

__device__ __forceinline__ float sigmoidf_(float x) {
    return 1.0f / (1.0f + expf(-x));
}
__device__ __forceinline__ float ld_agent(const float* p) {
    return __hip_atomic_load(p, __ATOMIC_RELAXED, __HIP_MEMORY_SCOPE_AGENT);
}
__device__ __forceinline__ void st_agent(float* p, float v) {
    __hip_atomic_store(p, v, __ATOMIC_RELAXED, __HIP_MEMORY_SCOPE_AGENT);
}
__device__ __forceinline__ int ld_agent_i(const int* p) {
    return __hip_atomic_load(p, __ATOMIC_RELAXED, __HIP_MEMORY_SCOPE_AGENT);
}

// 5 coherence-point (sc0 sc1) dwordx4 loads of 20 consecutive floats.
__device__ __forceinline__ void ld5x4_sc(const float* p, f32x4& a0, f32x4& a1,
                                         f32x4& a2, f32x4& a3, f32x4& a4) {
    asm volatile(
        "global_load_dwordx4 %0, %5, off sc0 sc1\n\t"
        "global_load_dwordx4 %1, %5, off offset:16 sc0 sc1\n\t"
        "global_load_dwordx4 %2, %5, off offset:32 sc0 sc1\n\t"
        "global_load_dwordx4 %3, %5, off offset:48 sc0 sc1\n\t"
        "global_load_dwordx4 %4, %5, off offset:64 sc0 sc1\n\t"
        "s_waitcnt vmcnt(0)"
        : "=&v"(a0), "=&v"(a1), "=&v"(a2), "=&v"(a3), "=&v"(a4)
        : "v"(p));
}
__device__ __forceinline__ u32x4 ld16_sc(const unsigned* p) {
    u32x4 v;
    asm volatile("global_load_dwordx4 %0, %1, off sc0 sc1\n\t"
                 "s_waitcnt vmcnt(0)"
                 : "=&v"(v) : "v"(p) : "memory");
    return v;
}
__device__ __forceinline__ void st16_sc(unsigned* p, u32x4 v) {
    asm volatile("global_store_dwordx4 %0, %1, off sc0 sc1"
                 :: "v"(p), "v"(v) : "memory");
}

// ---- Prep: WjhR[j][k] = Wj1[1024+k][j]; b1 = bih1 + bhh1 ----
__global__ void prep_t_kernel(const float* __restrict__ Wj1,
                              const float* __restrict__ bih1,
                              const float* __restrict__ bhh1,
                              float* __restrict__ WjhR, float* __restrict__ b1) {
    int idx = blockIdx.x * 256 + threadIdx.x;
    if (idx < 163840) {
        int j = idx / 320, k = idx - j * 320;
        WjhR[idx] = Wj1[(size_t)(1024 + k) * JHD + j];
        return;
    }
    int i2 = idx - 163840;
    if (i2 < G4) b1[i2] = bih1[i2] + bhh1[i2];
}

// ---- Prep: EP[v][j] = embed[v]@Wih0[j,:] + bih0[j]+bhh0[j]; row 28 = bias only
__global__ void ep_kernel(const float* __restrict__ embed,
                          const float* __restrict__ Wih0,
                          const float* __restrict__ bih0,
                          const float* __restrict__ bhh0,
                          float* __restrict__ EP) {
    __shared__ __align__(16) float es[HH];
    int v = blockIdx.x;
    for (int k = threadIdx.x; k < HH; k += 256)
        es[k] = (v < VV - 1) ? embed[v * HH + k] : 0.0f;
    __syncthreads();
    for (int j = threadIdx.x; j < G4; j += 256) {
        float acc = bih0[j] + bhh0[j];
        if (v < VV - 1) {
            const float4* wr = (const float4*)(Wih0 + (size_t)j * HH);
            const float4* ev = (const float4*)es;
            #pragma unroll 4
            for (int k4 = 0; k4 < HH / 4; ++k4) {
                float4 w = wr[k4], e = ev[k4];
                acc += w.x * e.x + w.y * e.y + w.z * e.z + w.w * e.w;
            }
        }
        EP[v * G4 + j] = acc;
    }
}

// ---- Encoder + F_proj fused ----
__global__ __launch_bounds__(512) void enc_fproj_kernel(
    const float* __restrict__ x, const float* __restrict__ Wenc,
    const float* __restrict__ benc, const float* __restrict__ Wj1,
    const float* __restrict__ bj1,
    float* __restrict__ logits_out, float* __restrict__ Fproj) {
    __shared__ float xs[8][F_IN];
    __shared__ float ls[8][E_DIM];
    int row0 = blockIdx.x * 8;
    int tid = threadIdx.x;
    for (int i = tid; i < 8 * F_IN; i += 512)
        xs[i / F_IN][i % F_IN] = x[(size_t)row0 * F_IN + i];
    __syncthreads();
    for (int j = tid; j < E_DIM; j += 512) {
        float acc[8];
        float bv = benc[j];
        #pragma unroll
        for (int r = 0; r < 8; ++r) acc[r] = bv;
        for (int k = 0; k < F_IN; ++k) {
            float w = Wenc[(size_t)k * E_DIM + j];
            #pragma unroll
            for (int r = 0; r < 8; ++r) acc[r] += xs[r][k] * w;
        }
        #pragma unroll
        for (int r = 0; r < 8; ++r) {
            ls[r][j] = acc[r];
            logits_out[(size_t)(row0 + r) * E_DIM + j] = acc[r];
        }
    }
    __syncthreads();
    {
        int j = tid;
        float acc[8];
        float bv = bj1[j];
        #pragma unroll
        for (int r = 0; r < 8; ++r) acc[r] = bv;
        for (int k = 0; k < E_DIM; ++k) {
            float w = Wj1[(size_t)k * JHD + j];
            #pragma unroll
            for (int r = 0; r < 8; ++r) acc[r] += ls[r][k] * w;
        }
        #pragma unroll
        for (int r = 0; r < 8; ++r) Fproj[(size_t)(row0 + r) * JHD + j] = acc[r];
    }
}

// ---- Init: zero sync; labels=-1; out_lens passthrough ----
__global__ void init_kernel(const int* __restrict__ lens, float* ws,
                            float* __restrict__ out_lens_out,
                            float* __restrict__ labels_out) {
    int tid = threadIdx.x;
    int* sync = (int*)(ws + OFF_SYNC);
    if (tid < 128) sync[tid] = 0;
    for (int i = tid; i < BB * LBUF; i += 1024) labels_out[i] = -1.0f;
    if (tid < BB) out_lens_out[tid] = (float)lens[tid];
}

// arrive + busy-wait barrier (central counter, single release word, no sleep)
__device__ __forceinline__ void arrive_wait(int* cnt, int* rel, int e) {
    asm volatile("s_waitcnt vmcnt(0)" ::: "memory");
    __syncthreads();
    if (threadIdx.x == 0) {
        int old = __hip_atomic_fetch_add(cnt, 1, __ATOMIC_RELAXED,
                                         __HIP_MEMORY_SCOPE_AGENT);
        if (old == e * NB - 1) {
            __hip_atomic_store(rel, e, __ATOMIC_RELAXED, __HIP_MEMORY_SCOPE_AGENT);
        } else {
            while (ld_agent_i(rel) < e) { }
        }
    }
    asm volatile("" ::: "memory");
    __syncthreads();
}

// ---- Persistent lockstep decoder: 16 blocks x 1024 threads ----
__global__ __launch_bounds__(1024) void decode_persistent(
    const int* __restrict__ lens,
    const float* __restrict__ Fproj,
    const float* __restrict__ W0,    // Whh0 [1280][320]
    const float* __restrict__ W1a,   // Wih1 [1280][320]
    const float* __restrict__ W1b,   // Whh1 [1280][320]
    const float* __restrict__ WjhR,  // [512][320]
    const float* __restrict__ Wj2,   // [512][29]
    const float* __restrict__ EP, const float* __restrict__ b1,
    const float* __restrict__ bj2,
    float* H0P, float* H1P, float* plog, int* syncw,
    float* __restrict__ labels_out, float* __restrict__ counts_out) {

    const int tid = threadIdx.x;
    const int blk = blockIdx.x;
    int* cnt1 = syncw;        int* rel1 = syncw + 16;
    int* cnt2 = syncw + 32;   int* rel2 = syncw + 48;
    int* cnt3 = syncw + 64;
    unsigned* pay = (unsigned*)(syncw + 80);   // 16B aligned, own 64B line

    __shared__ __align__(16) float h0c[16 * HPITCH];
    __shared__ __align__(16) float h1c[16 * HPITCH];
    __shared__ float sh_g[80 * 17];
    __shared__ float sh_lg[16 * 30];
    __shared__ int sh_dec[16];
    __shared__ unsigned sh_pay[3];
    __shared__ int lastL[16], cntL[16], contL[16], lenL[16], emitL[16];
    __shared__ int sMaxL;

    for (int i = tid; i < 16 * HPITCH; i += 1024) { h0c[i] = 0.f; h1c[i] = 0.f; }
    if (tid < 16) {
        lastL[tid] = BLANKV; cntL[tid] = 0; contL[tid] = 0;
        lenL[tid] = lens[tid];
    }
    if (tid == 0) {
        int m = 0;
        for (int i = 0; i < BB; ++i) m = max(m, lens[i]);
        sMaxL = m;
    }
    __syncthreads();
    const int maxL = sMaxL;

    // matvec lane decomposition: b_lo(2b) kc(4b) bh(2b) jg(2b)
    const int b_lo = tid & 3;
    const int kc   = (tid >> 2) & 15;
    const int bh   = (tid >> 6) & 3;
    const int jg   = tid >> 8;          // gate group / j-group
    const int b    = (bh << 2) | b_lo;
    const int kf   = kc * 20;

    // update threads: tid<320 -> (ub=tid&15, il=tid>>4 in 0..19)
    const int ub = tid & 15, il = tid >> 4;
    float c0cur = 0.f, c1cur = 0.f, c0p = 0.f, c1p = 0.f;

    for (int slot = 0; slot < 3 * maxL; ++slot) {
        const int t = slot / 3;
        const int s = slot - t * 3;
        const int e = slot + 1;

        // ========== Phase A: LSTM cell 0 (h0_cur from LDS, no global reads) ==========
        {
            const float4* hv = (const float4*)(h0c + b * HPITCH + kf);
            const float*  w0 = W0 + (size_t)(jg * 320 + blk * 20) * 320 + kf;
            float acc[20];
            #pragma unroll
            for (int jj = 0; jj < 20; ++jj) acc[jj] = 0.f;
            #pragma unroll
            for (int q = 0; q < 5; ++q) {
                float4 h = hv[q];
                #pragma unroll
                for (int jj = 0; jj < 20; ++jj) {
                    float4 w = *(const float4*)(w0 + jj * 320 + q * 4);
                    acc[jj] += h.x * w.x + h.y * w.y + h.z * w.z + h.w * w.w;
                }
            }
            #pragma unroll
            for (int jj = 0; jj < 20; ++jj) {
                float a = acc[jj];
                a += __shfl_xor(a, 4);  a += __shfl_xor(a, 8);
                a += __shfl_xor(a, 16); a += __shfl_xor(a, 32);
                acc[jj] = a;
            }
            if (kc == 0) {
                const float* ep = EP + (size_t)lastL[b] * G4 + jg * 320 + blk * 20;
                #pragma unroll
                for (int jj = 0; jj < 20; ++jj)
                    sh_g[(jg * 20 + jj) * 17 + b] = acc[jj] + ep[jj];
            }
        }
        __syncthreads();
        if (tid < 320) {
            float xi = sh_g[(0 * 20 + il) * 17 + ub];
            float xf = sh_g[(1 * 20 + il) * 17 + ub];
            float xg = sh_g[(2 * 20 + il) * 17 + ub];
            float xo = sh_g[(3 * 20 + il) * 17 + ub];
            c0p = sigmoidf_(xf) * c0cur + sigmoidf_(xi) * tanhf(xg);
            st_agent(H0P + ub * 320 + blk * 20 + il, sigmoidf_(xo) * tanhf(c0p));
        }
        arrive_wait(cnt1, rel1, e);

        // ========== Phase B: LSTM cell 1 (h0_pend direct sc1 loads; h1_cur LDS) ==========
        {
            f32x4 p0, p1, p2, p3, p4;
            ld5x4_sc(H0P + b * 320 + kf, p0, p1, p2, p3, p4);
            const float4* hb = (const float4*)(h1c + b * HPITCH + kf);
            const float*  wa = W1a + (size_t)(jg * 320 + blk * 20) * 320 + kf;
            const float*  wb = W1b + (size_t)(jg * 320 + blk * 20) * 320 + kf;
            float acc[20];
            #pragma unroll
            for (int jj = 0; jj < 20; ++jj) acc[jj] = 0.f;
            f32x4 hp[5] = {p0, p1, p2, p3, p4};
            #pragma unroll
            for (int q = 0; q < 5; ++q) {
                f32x4 x = hp[q];
                float4 y = hb[q];
                #pragma unroll
                for (int jj = 0; jj < 20; ++jj) {
                    float4 w1 = *(const float4*)(wa + jj * 320 + q * 4);
                    float4 w2 = *(const float4*)(wb + jj * 320 + q * 4);
                    acc[jj] += x[0] * w1.x + x[1] * w1.y + x[2] * w1.z + x[3] * w1.w
                             + y.x * w2.x + y.y * w2.y + y.z * w2.z + y.w * w2.w;
                }
            }
            #pragma unroll
            for (int jj = 0; jj < 20; ++jj) {
                float a = acc[jj];
                a += __shfl_xor(a, 4);  a += __shfl_xor(a, 8);
                a += __shfl_xor(a, 16); a += __shfl_xor(a, 32);
                acc[jj] = a;
            }
            if (kc == 0) {
                const float* bb1 = b1 + jg * 320 + blk * 20;
                #pragma unroll
                for (int jj = 0; jj < 20; ++jj)
                    sh_g[(jg * 20 + jj) * 17 + b] = acc[jj] + bb1[jj];
            }
        }
        __syncthreads();
        if (tid < 320) {
            float xi = sh_g[(0 * 20 + il) * 17 + ub];
            float xf = sh_g[(1 * 20 + il) * 17 + ub];
            float xg = sh_g[(2 * 20 + il) * 17 + ub];
            float xo = sh_g[(3 * 20 + il) * 17 + ub];
            c1p = sigmoidf_(xf) * c1cur + sigmoidf_(xi) * tanhf(xg);
            st_agent(H1P + ub * 320 + blk * 20 + il, sigmoidf_(xo) * tanhf(c1p));
        }
        arrive_wait(cnt2, rel2, e);

        // ========== Phase C: jh slice (32 j) + compact partial logits ==========
        {
            f32x4 p0, p1, p2, p3, p4;
            ld5x4_sc(H1P + b * 320 + kf, p0, p1, p2, p3, p4);
            const float* wc = WjhR + (size_t)(blk * 32 + jg * 8) * 320 + kf;
            float acc[8] = {0.f,0.f,0.f,0.f,0.f,0.f,0.f,0.f};
            f32x4 hp[5] = {p0, p1, p2, p3, p4};
            #pragma unroll
            for (int q = 0; q < 5; ++q) {
                f32x4 h = hp[q];
                #pragma unroll
                for (int jj = 0; jj < 8; ++jj) {
                    float4 w = *(const float4*)(wc + jj * 320 + q * 4);
                    acc[jj] += h[0] * w.x + h[1] * w.y + h[2] * w.z + h[3] * w.w;
                }
            }
            #pragma unroll
            for (int jj = 0; jj < 8; ++jj) {
                float a = acc[jj];
                a += __shfl_xor(a, 4);  a += __shfl_xor(a, 8);
                a += __shfl_xor(a, 16); a += __shfl_xor(a, 32);
                acc[jj] = a;
            }
            if (kc == 0) {
                const float* fp = Fproj + ((size_t)b * TT + t) * JHD + blk * 32 + jg * 8;
                #pragma unroll
                for (int jj = 0; jj < 8; ++jj)
                    sh_g[(jg * 8 + jj) * 17 + b] = fmaxf(fp[jj] + acc[jj], 0.f);
            }
        }
        __syncthreads();
        if (tid < 464) {
            int b2 = tid / 29, v = tid - b2 * 29;
            float p = 0.f;
            #pragma unroll
            for (int jl = 0; jl < 32; ++jl)
                p += sh_g[jl * 17 + b2] * Wj2[(size_t)(blk * 32 + jl) * VV + v];
            st_agent(plog + blk * 464 + tid, p);
        }
        // arrive at bar3 (no shared release; root computes D and broadcasts payload)
        asm volatile("s_waitcnt vmcnt(0)" ::: "memory");
        __syncthreads();
        if (tid == 0)
            __hip_atomic_fetch_add(cnt3, 1, __ATOMIC_RELAXED, __HIP_MEMORY_SCOPE_AGENT);

        // ========== Phase D (root) / payload poll (others) ==========
        if (blk == 0) {
            if (tid == 0) { while (ld_agent_i(cnt3) < e * NB) { } }
            __syncthreads();
            if (tid < 464) {
                int b2 = tid / 29, v = tid - b2 * 29;
                float acc = bj2[v];
                #pragma unroll
                for (int r = 0; r < NB; ++r)
                    acc += ld_agent(plog + r * 464 + tid);
                sh_lg[b2 * 30 + v] = acc;
            }
            __syncthreads();
            if (tid < 16) {
                float best = sh_lg[tid * 30];
                int k = 0;
                #pragma unroll
                for (int v = 1; v < VV; ++v) {
                    float x = sh_lg[tid * 30 + v];
                    if (x > best) { best = x; k = v; }
                }
                bool active = (t < lenL[tid]) && (s == 0 || contL[tid]);
                bool emit = active && (k != BLANKV);
                sh_dec[tid] = emit ? k : 63;
                if (emit)
                    labels_out[(size_t)tid * LBUF + cntL[tid]] = (float)k;
            }
            __syncthreads();
            if (tid == 0) {
                unsigned y = 0, z = 0, w = 0;
                #pragma unroll
                for (int i = 0; i < 5; ++i) {
                    y |= (unsigned)sh_dec[i]      << (6 * i);
                    z |= (unsigned)sh_dec[5 + i]  << (6 * i);
                    w |= (unsigned)sh_dec[10 + i] << (6 * i);
                }
                unsigned c15 = (unsigned)sh_dec[15];
                y |= (c15 & 3u) << 30;
                z |= ((c15 >> 2) & 3u) << 30;
                w |= ((c15 >> 4) & 3u) << 30;
                u32x4 p; p[0] = (unsigned)e; p[1] = y; p[2] = z; p[3] = w;
                st16_sc(pay, p);
            }
        } else {
            if (tid == 0) {
                u32x4 p;
                do { p = ld16_sc(pay); } while ((int)p[0] < e);
                sh_pay[0] = p[1]; sh_pay[1] = p[2]; sh_pay[2] = p[3];
            }
            __syncthreads();
            if (tid < 16) {
                int code;
                if (tid < 15) code = (int)((sh_pay[tid / 5] >> (6 * (tid % 5))) & 63u);
                else code = (int)(((sh_pay[0] >> 30) & 3u) |
                                  (((sh_pay[1] >> 30) & 3u) << 2) |
                                  (((sh_pay[2] >> 30) & 3u) << 4));
                sh_dec[tid] = code;
            }
        }
        __syncthreads();

        // ========== Commit (all blocks, local) ==========
        if (tid < 16) {
            int code = sh_dec[tid];
            int em = (code != 63);
            emitL[tid] = em;
            if (em) { lastL[tid] = code; cntL[tid] += 1; contL[tid] = 1; }
            else    { contL[tid] = 0; }
        }
        __syncthreads();
        for (int idx = tid; idx < 5120; idx += 1024) {
            int ib = idx / 320, k = idx - ib * 320;
            if (emitL[ib]) {
                h0c[ib * HPITCH + k] = ld_agent(H0P + idx);
                h1c[ib * HPITCH + k] = ld_agent(H1P + idx);
            }
        }
        if (tid < 320 && emitL[ub]) { c0cur = c0p; c1cur = c1p; }
        __syncthreads();
    }

    if (blk == 0 && tid < 16) counts_out[tid] = (float)cntL[tid];
}

extern "C" void kernel_launch(void* const* d_in, const int* in_sizes, int n_in,
                              void* d_out, int out_size, void* d_ws, size_t ws_size,
                              hipStream_t stream) {
    const float* x      = (const float*)d_in[0];
    const int*   lens   = (const int*)d_in[1];
    const float* Wenc   = (const float*)d_in[2];
    const float* benc   = (const float*)d_in[3];
    const float* embed  = (const float*)d_in[4];
    const float* Wih0   = (const float*)d_in[5];
    const float* Whh0   = (const float*)d_in[6];
    const float* bih0   = (const float*)d_in[7];
    const float* bhh0   = (const float*)d_in[8];
    const float* Wih1   = (const float*)d_in[9];
    const float* Whh1   = (const float*)d_in[10];
    const float* bih1   = (const float*)d_in[11];
    const float* bhh1   = (const float*)d_in[12];
    const float* Wj1    = (const float*)d_in[13];
    const float* bj1    = (const float*)d_in[14];
    const float* Wj2    = (const float*)d_in[15];
    const float* bj2    = (const float*)d_in[16];

    float* out = (float*)d_out;
    float* logits_out   = out;
    float* out_lens_out = out + (size_t)BB * TT * E_DIM;
    float* labels_out   = out_lens_out + BB;
    float* counts_out   = labels_out + (size_t)BB * LBUF;

    float* ws    = (float*)d_ws;
    float* Fproj = ws + OFF_FPROJ;
    float* WjhR  = ws + OFF_WJHR;
    float* EP    = ws + OFF_EP;
    float* b1    = ws + OFF_B1;
    float* H0P   = ws + OFF_H0P;
    float* H1P   = ws + OFF_H1P;
    float* plog  = ws + OFF_PLOG;
    int*   syncw = (int*)(ws + OFF_SYNC);

    {
        int total = 163840 + G4;
        prep_t_kernel<<<(total + 255) / 256, 256, 0, stream>>>(Wj1, bih1, bhh1, WjhR, b1);
    }
    ep_kernel<<<VV, 256, 0, stream>>>(embed, Wih0, bih0, bhh0, EP);
    enc_fproj_kernel<<<(BB * TT) / 8, 512, 0, stream>>>(x, Wenc, benc, Wj1, bj1,
                                                        logits_out, Fproj);
    init_kernel<<<1, 1024, 0, stream>>>(lens, ws, out_lens_out, labels_out);
    decode_persistent<<<NB, 1024, 0, stream>>>(lens, Fproj, Whh0, Wih1, Whh1,
                                               WjhR, Wj2, EP, b1, bj2,
                                               H0P, H1P, plog, syncw,
                                               labels_out, counts_out);
}

// Round 6
// 19246.991 us; speedup vs baseline: 2.6385x; 2.6385x over previous
//
#include <hip/hip_runtime.h>
#include <math.h>

// Problem constants
#define BB 16
#define TT 128
#define F_IN 240
#define E_DIM 1024
#define HH 320
#define G4 1280
#define JHD 512
#define VV 29
#define BLANKV 28
#define MAXSYM 3
#define LBUF (TT*MAXSYM)

#define NB 32          // persistent blocks, 10 h-rows + 16 joint-j each
#define ROWS 10
#define JBLK 16
#define LPITCH 324     // LDS row pitch (floats, 16B-aligned, banks balanced)

// Workspace layout (float offsets)
#define OFF_FPROJ 0ul                        // 2048*512
#define OFF_WJHR  1048576ul                  // 512*320
#define OFF_EP    (OFF_WJHR + 163840ul)      // 29*1280
#define OFF_B1    (OFF_EP + 37120ul)         // 1280
#define OFF_MA    (OFF_B1 + 1280ul)          // 16*320 pending h0
#define OFF_MB    (OFF_MA + 5120ul)          // 16*320 pending h1
#define OFF_PL    (OFF_MB + 5120ul)          // 32*464 partial logits
#define OFF_SYNC  (OFF_PL + 14848ul)         // 2048 ints: tags + payload

typedef float f32x4 __attribute__((ext_vector_type(4)));
typedef unsigned u32x4 __attribute__((ext_vector_type(4)));

__device__ __forceinline__ float sigmoidf_(float x) {
    return 1.0f / (1.0f + expf(-x));
}
__device__ __forceinline__ float ld_agent(const float* p) {
    return __hip_atomic_load(p, __ATOMIC_RELAXED, __HIP_MEMORY_SCOPE_AGENT);
}
__device__ __forceinline__ void st_agent(float* p, float v) {
    __hip_atomic_store(p, v, __ATOMIC_RELAXED, __HIP_MEMORY_SCOPE_AGENT);
}
__device__ __forceinline__ int ld_agent_i(const int* p) {
    return __hip_atomic_load(p, __ATOMIC_RELAXED, __HIP_MEMORY_SCOPE_AGENT);
}
__device__ __forceinline__ void st_agent_i(int* p, int v) {
    __hip_atomic_store(p, v, __ATOMIC_RELAXED, __HIP_MEMORY_SCOPE_AGENT);
}
__device__ __forceinline__ u32x4 ld16_sc(const unsigned* p) {
    u32x4 v;
    asm volatile("global_load_dwordx4 %0, %1, off sc0 sc1\n\t"
                 "s_waitcnt vmcnt(0)"
                 : "=&v"(v) : "v"(p) : "memory");
    return v;
}
__device__ __forceinline__ void st16_sc(unsigned* p, u32x4 v) {
    asm volatile("global_store_dwordx4 %0, %1, off sc0 sc1"
                 :: "v"(p), "v"(v) : "memory");
}

// ---- Prep: WjhR[j][k] = Wj1[1024+k][j]; b1 = bih1 + bhh1 ----
__global__ void prep_t_kernel(const float* __restrict__ Wj1,
                              const float* __restrict__ bih1,
                              const float* __restrict__ bhh1,
                              float* __restrict__ WjhR, float* __restrict__ b1) {
    int idx = blockIdx.x * 256 + threadIdx.x;
    if (idx < 163840) {
        int j = idx / 320, k = idx - j * 320;
        WjhR[idx] = Wj1[(size_t)(1024 + k) * JHD + j];
        return;
    }
    int i2 = idx - 163840;
    if (i2 < G4) b1[i2] = bih1[i2] + bhh1[i2];
}

// ---- Prep: EP[v][j] = embed[v]@Wih0[j,:] + bih0[j]+bhh0[j]; row 28 = bias only
__global__ void ep_kernel(const float* __restrict__ embed,
                          const float* __restrict__ Wih0,
                          const float* __restrict__ bih0,
                          const float* __restrict__ bhh0,
                          float* __restrict__ EP) {
    __shared__ __align__(16) float es[HH];
    int v = blockIdx.x;
    for (int k = threadIdx.x; k < HH; k += 256)
        es[k] = (v < VV - 1) ? embed[v * HH + k] : 0.0f;
    __syncthreads();
    for (int j = threadIdx.x; j < G4; j += 256) {
        float acc = bih0[j] + bhh0[j];
        if (v < VV - 1) {
            const float4* wr = (const float4*)(Wih0 + (size_t)j * HH);
            const float4* ev = (const float4*)es;
            #pragma unroll 4
            for (int k4 = 0; k4 < HH / 4; ++k4) {
                float4 w = wr[k4], e = ev[k4];
                acc += w.x * e.x + w.y * e.y + w.z * e.z + w.w * e.w;
            }
        }
        EP[v * G4 + j] = acc;
    }
}

// ---- Encoder + F_proj fused ----
__global__ __launch_bounds__(512) void enc_fproj_kernel(
    const float* __restrict__ x, const float* __restrict__ Wenc,
    const float* __restrict__ benc, const float* __restrict__ Wj1,
    const float* __restrict__ bj1,
    float* __restrict__ logits_out, float* __restrict__ Fproj) {
    __shared__ float xs[8][F_IN];
    __shared__ float ls[8][E_DIM];
    int row0 = blockIdx.x * 8;
    int tid = threadIdx.x;
    for (int i = tid; i < 8 * F_IN; i += 512)
        xs[i / F_IN][i % F_IN] = x[(size_t)row0 * F_IN + i];
    __syncthreads();
    for (int j = tid; j < E_DIM; j += 512) {
        float acc[8];
        float bv = benc[j];
        #pragma unroll
        for (int r = 0; r < 8; ++r) acc[r] = bv;
        for (int k = 0; k < F_IN; ++k) {
            float w = Wenc[(size_t)k * E_DIM + j];
            #pragma unroll
            for (int r = 0; r < 8; ++r) acc[r] += xs[r][k] * w;
        }
        #pragma unroll
        for (int r = 0; r < 8; ++r) {
            ls[r][j] = acc[r];
            logits_out[(size_t)(row0 + r) * E_DIM + j] = acc[r];
        }
    }
    __syncthreads();
    {
        int j = tid;
        float acc[8];
        float bv = bj1[j];
        #pragma unroll
        for (int r = 0; r < 8; ++r) acc[r] = bv;
        for (int k = 0; k < E_DIM; ++k) {
            float w = Wj1[(size_t)k * JHD + j];
            #pragma unroll
            for (int r = 0; r < 8; ++r) acc[r] += ls[r][k] * w;
        }
        #pragma unroll
        for (int r = 0; r < 8; ++r) Fproj[(size_t)(row0 + r) * JHD + j] = acc[r];
    }
}

// ---- Init: zero sync words; labels=-1; out_lens passthrough ----
__global__ void init_kernel(const int* __restrict__ lens, float* ws,
                            float* __restrict__ out_lens_out,
                            float* __restrict__ labels_out) {
    int tid = threadIdx.x;
    int* sync = (int*)(ws + OFF_SYNC);
    for (int i = tid; i < 2048; i += 1024) sync[i] = 0;
    for (int i = tid; i < BB * LBUF; i += 1024) labels_out[i] = -1.0f;
    if (tid < BB) out_lens_out[tid] = (float)lens[tid];
}

// ---- Persistent lockstep decoder: 32 blocks x 1024 threads ----
// Protocol per slot: A(tag) -> B(tag) -> C(tag) -> root D -> payload.
// Single-buffered mailboxes are safe: payload[e] is causally after every
// block's phase-C of slot e, so writes for e+1 follow all reads of e.
__global__ __launch_bounds__(1024) void decode_persistent(
    const int* __restrict__ lens,
    const float* __restrict__ Fproj,
    const float* __restrict__ W0,    // Whh0 [1280][320]
    const float* __restrict__ W1a,   // Wih1 [1280][320]
    const float* __restrict__ W1b,   // Whh1 [1280][320]
    const float* __restrict__ WjhR,  // [512][320]
    const float* __restrict__ Wj2,   // [512][29]
    const float* __restrict__ EP, const float* __restrict__ b1,
    const float* __restrict__ bj2,
    float* MA, float* MB, float* PL, int* syncw,
    float* __restrict__ labels_out, float* __restrict__ counts_out) {

    const int tid = threadIdx.x;
    const int blk = blockIdx.x;
    int* Atag = syncw;            // 32 tags, 64B apart
    int* Btag = syncw + 512;
    int* Ctag = syncw + 1024;
    unsigned* pay = (unsigned*)(syncw + 1536);

    extern __shared__ float dyn[];
    float* h0c = dyn;                    // [16][LPITCH] current h0
    float* h1c = dyn + 16 * LPITCH;      // current h1
    float* h0p = dyn + 32 * LPITCH;      // staged pending h0
    float* h1p = dyn + 48 * LPITCH;      // staged pending h1

    __shared__ float sh_jh[16 * 17];
    __shared__ float sh_lg[16 * 30];
    __shared__ int sh_dec[16];
    __shared__ unsigned sh_pay[3];
    __shared__ int lastL[16], cntL[16], contL[16], lenL[16], emitL[16];
    __shared__ int sMaxL;

    for (int i = tid; i < 32 * LPITCH; i += 1024) { h0c[i] = 0.f; h1c[i] = 0.f; }
    if (tid < 16) {
        lastL[tid] = BLANKV; cntL[tid] = 0; contL[tid] = 0;
        lenL[tid] = lens[tid];
    }
    if (tid == 0) {
        int m = 0;
        for (int i = 0; i < BB; ++i) m = max(m, lens[i]);
        sMaxL = m;
    }
    __syncthreads();
    const int maxL = sMaxL;

    // matvec lanes (A/B): tid<640: b | ks<<4 | rh<<6 (shfl 16,32 reduces ks)
    const int b  = tid & 15;
    const int ks = (tid >> 4) & 3;
    const int rh = tid >> 6;
    const bool mv = tid < 640;
    const int row = blk * ROWS + rh;
    const int kf = ks * 80;

    float c0cur = 0.f, c1cur = 0.f, c0p = 0.f, c1p = 0.f;
    float g1p0 = 0.f, g1p1 = 0.f, g1p2 = 0.f, g1p3 = 0.f;

    for (int slot = 0; slot < 3 * maxL; ++slot) {
        const int t = slot / 3;
        const int s = slot - t * 3;
        const int e = slot + 1;

        // ===== Phase A: gates0 = Whh0@h0cur (+EP); also g1p = Whh1@h1cur =====
        if (mv) {
            const float4* h0v = (const float4*)(h0c + b * LPITCH + kf);
            const float4* h1v = (const float4*)(h1c + b * LPITCH + kf);
            const float* w0 = W0  + (size_t)row * 320 + kf;
            const float* wb = W1b + (size_t)row * 320 + kf;
            float g0[4] = {0.f, 0.f, 0.f, 0.f};
            float g1[4] = {0.f, 0.f, 0.f, 0.f};
            #pragma unroll 5
            for (int u = 0; u < 20; ++u) {
                float4 h0 = h0v[u], h1 = h1v[u];
                #pragma unroll
                for (int g = 0; g < 4; ++g) {
                    float4 w = *(const float4*)(w0 + (size_t)g * 102400 + u * 4);
                    g0[g] += h0.x * w.x + h0.y * w.y + h0.z * w.z + h0.w * w.w;
                    float4 v2 = *(const float4*)(wb + (size_t)g * 102400 + u * 4);
                    g1[g] += h1.x * v2.x + h1.y * v2.y + h1.z * v2.z + h1.w * v2.w;
                }
            }
            g1p0 = g1[0]; g1p1 = g1[1]; g1p2 = g1[2]; g1p3 = g1[3];
            #pragma unroll
            for (int g = 0; g < 4; ++g) {
                g0[g] += __shfl_xor(g0[g], 16);
                g0[g] += __shfl_xor(g0[g], 32);
            }
            if (ks == 0) {
                const float* ep = EP + (size_t)lastL[b] * G4 + row;
                float xi = g0[0] + ep[0];
                float xf = g0[1] + ep[320];
                float xg = g0[2] + ep[640];
                float xo = g0[3] + ep[960];
                c0p = sigmoidf_(xf) * c0cur + sigmoidf_(xi) * tanhf(xg);
                st_agent(MA + b * 320 + row, sigmoidf_(xo) * tanhf(c0p));
            }
        }
        asm volatile("s_waitcnt vmcnt(0)" ::: "memory");
        __syncthreads();
        if (tid == 0) st_agent_i(Atag + blk * 16, e);

        // ===== Phase B: gates1 = g1p + Wih1@h0p + b1 =====
        if (tid < 64) {
            const int* tp = Atag + (tid & 31) * 16;
            while (__ballot((tid < 32) && (ld_agent_i(tp) < e)) != 0ull)
                __builtin_amdgcn_s_sleep(1);
        }
        __syncthreads();
        for (int idx = tid; idx < 5120; idx += 1024) {
            int ib = idx / 320, k = idx - ib * 320;
            h0p[ib * LPITCH + k] = ld_agent(MA + idx);
        }
        __syncthreads();
        if (mv) {
            const float4* hv = (const float4*)(h0p + b * LPITCH + kf);
            const float* wa = W1a + (size_t)row * 320 + kf;
            float g1[4] = {g1p0, g1p1, g1p2, g1p3};
            #pragma unroll 5
            for (int u = 0; u < 20; ++u) {
                float4 h = hv[u];
                #pragma unroll
                for (int g = 0; g < 4; ++g) {
                    float4 w = *(const float4*)(wa + (size_t)g * 102400 + u * 4);
                    g1[g] += h.x * w.x + h.y * w.y + h.z * w.z + h.w * w.w;
                }
            }
            #pragma unroll
            for (int g = 0; g < 4; ++g) {
                g1[g] += __shfl_xor(g1[g], 16);
                g1[g] += __shfl_xor(g1[g], 32);
            }
            if (ks == 0) {
                float xi = g1[0] + b1[0 * 320 + row];
                float xf = g1[1] + b1[1 * 320 + row];
                float xg = g1[2] + b1[2 * 320 + row];
                float xo = g1[3] + b1[3 * 320 + row];
                c1p = sigmoidf_(xf) * c1cur + sigmoidf_(xi) * tanhf(xg);
                st_agent(MB + b * 320 + row, sigmoidf_(xo) * tanhf(c1p));
            }
        }
        asm volatile("s_waitcnt vmcnt(0)" ::: "memory");
        __syncthreads();
        if (tid == 0) st_agent_i(Btag + blk * 16, e);

        // ===== Phase C: jh slice (16 j) + partial logits =====
        if (tid < 64) {
            const int* tp = Btag + (tid & 31) * 16;
            while (__ballot((tid < 32) && (ld_agent_i(tp) < e)) != 0ull)
                __builtin_amdgcn_s_sleep(1);
        }
        __syncthreads();
        for (int idx = tid; idx < 5120; idx += 1024) {
            int ib = idx / 320, k = idx - ib * 320;
            h1p[ib * LPITCH + k] = ld_agent(MB + idx);
        }
        __syncthreads();
        if (tid < 512) {
            int ks2 = (tid >> 4) & 3, j5 = tid >> 6;   // 0..7
            int j0 = blk * JBLK + j5, j1_ = j0 + 8;
            const float4* hv = (const float4*)(h1p + b * LPITCH + ks2 * 80);
            const float* wc0 = WjhR + (size_t)j0 * 320 + ks2 * 80;
            const float* wc1 = WjhR + (size_t)j1_ * 320 + ks2 * 80;
            float p0 = 0.f, p1 = 0.f;
            #pragma unroll 5
            for (int u = 0; u < 20; ++u) {
                float4 h = hv[u];
                float4 w = *(const float4*)(wc0 + u * 4);
                p0 += h.x * w.x + h.y * w.y + h.z * w.z + h.w * w.w;
                float4 w2 = *(const float4*)(wc1 + u * 4);
                p1 += h.x * w2.x + h.y * w2.y + h.z * w2.z + h.w * w2.w;
            }
            p0 += __shfl_xor(p0, 16); p0 += __shfl_xor(p0, 32);
            p1 += __shfl_xor(p1, 16); p1 += __shfl_xor(p1, 32);
            if (ks2 == 0) {
                const float* fp = Fproj + ((size_t)(b * TT + t)) * JHD;
                sh_jh[b * 17 + j5]     = fmaxf(p0 + fp[j0], 0.f);
                sh_jh[b * 17 + j5 + 8] = fmaxf(p1 + fp[j1_], 0.f);
            }
        }
        __syncthreads();
        if (tid < 464) {
            int b2 = tid / 29, v = tid - b2 * 29;
            float p = 0.f;
            #pragma unroll
            for (int jl = 0; jl < 16; ++jl)
                p += sh_jh[b2 * 17 + jl] * Wj2[(size_t)(blk * JBLK + jl) * VV + v];
            st_agent(PL + blk * 464 + tid, p);
        }
        asm volatile("s_waitcnt vmcnt(0)" ::: "memory");
        __syncthreads();
        if (tid == 0) st_agent_i(Ctag + blk * 16, e);

        // ===== Phase D: root reduces + argmax + 16B payload broadcast =====
        if (blk == 0) {
            if (tid < 64) {
                const int* tp = Ctag + (tid & 31) * 16;
                while (__ballot((tid < 32) && (ld_agent_i(tp) < e)) != 0ull)
                    __builtin_amdgcn_s_sleep(1);
            }
            __syncthreads();
            if (tid < 464) {
                int b2 = tid / 29, v = tid - b2 * 29;
                float acc = bj2[v];
                #pragma unroll
                for (int r2 = 0; r2 < NB; ++r2)
                    acc += ld_agent(PL + r2 * 464 + tid);
                sh_lg[b2 * 30 + v] = acc;
            }
            __syncthreads();
            if (tid < 16) {
                float best = sh_lg[tid * 30];
                int k = 0;
                #pragma unroll
                for (int v = 1; v < VV; ++v) {
                    float x = sh_lg[tid * 30 + v];
                    if (x > best) { best = x; k = v; }
                }
                bool active = (t < lenL[tid]) && (s == 0 || contL[tid]);
                bool emit = active && (k != BLANKV);
                sh_dec[tid] = emit ? k : 63;
                if (emit)
                    labels_out[(size_t)tid * LBUF + cntL[tid]] = (float)k;
            }
            __syncthreads();
            if (tid == 0) {
                unsigned y = 0, z = 0, w = 0;
                #pragma unroll
                for (int i = 0; i < 5; ++i) {
                    y |= (unsigned)sh_dec[i]      << (6 * i);
                    z |= (unsigned)sh_dec[5 + i]  << (6 * i);
                    w |= (unsigned)sh_dec[10 + i] << (6 * i);
                }
                unsigned c15 = (unsigned)sh_dec[15];
                y |= (c15 & 3u) << 30;
                z |= ((c15 >> 2) & 3u) << 30;
                w |= ((c15 >> 4) & 3u) << 30;
                u32x4 p; p[0] = (unsigned)e; p[1] = y; p[2] = z; p[3] = w;
                st16_sc(pay, p);
            }
        } else {
            if (tid == 0) {
                u32x4 p;
                do { p = ld16_sc(pay); } while ((int)p[0] < e);
                sh_pay[0] = p[1]; sh_pay[1] = p[2]; sh_pay[2] = p[3];
            }
            __syncthreads();
            if (tid < 16) {
                int code;
                if (tid < 15) code = (int)((sh_pay[tid / 5] >> (6 * (tid % 5))) & 63u);
                else code = (int)(((sh_pay[0] >> 30) & 3u) |
                                  (((sh_pay[1] >> 30) & 3u) << 2) |
                                  (((sh_pay[2] >> 30) & 3u) << 4));
                sh_dec[tid] = code;
            }
        }
        __syncthreads();

        // ===== Commit: flags + LDS-to-LDS copy, zero global traffic =====
        if (tid < 16) {
            int code = sh_dec[tid];
            int em = (code != 63);
            emitL[tid] = em;
            if (em) { lastL[tid] = code; cntL[tid] += 1; contL[tid] = 1; }
            else    { contL[tid] = 0; }
        }
        __syncthreads();
        for (int idx = tid; idx < 1280; idx += 1024) {
            int ib = idx / 80, q = idx - ib * 80;
            if (emitL[ib]) {
                ((float4*)(h0c + ib * LPITCH))[q] = ((const float4*)(h0p + ib * LPITCH))[q];
                ((float4*)(h1c + ib * LPITCH))[q] = ((const float4*)(h1p + ib * LPITCH))[q];
            }
        }
        if (mv && ks == 0 && emitL[b]) { c0cur = c0p; c1cur = c1p; }
        __syncthreads();
    }

    if (blk == 0 && tid < 16) counts_out[tid] = (float)cntL[tid];
}

extern "C" void kernel_launch(void* const* d_in, const int* in_sizes, int n_in,
                              void* d_out, int out_size, void* d_ws, size_t ws_size,
                              hipStream_t stream) {
    const float* x      = (const float*)d_in[0];
    const int*   lens   = (const int*)d_in[1];
    const float* Wenc   = (const float*)d_in[2];
    const float* benc   = (const float*)d_in[3];
    const float* embed  = (const float*)d_in[4];
    const float* Wih0   = (const float*)d_in[5];
    const float* Whh0   = (const float*)d_in[6];
    const float* bih0   = (const float*)d_in[7];
    const float* bhh0   = (const float*)d_in[8];
    const float* Wih1   = (const float*)d_in[9];
    const float* Whh1   = (const float*)d_in[10];
    const float* bih1   = (const float*)d_in[11];
    const float* bhh1   = (const float*)d_in[12];
    const float* Wj1    = (const float*)d_in[13];
    const float* bj1    = (const float*)d_in[14];
    const float* Wj2    = (const float*)d_in[15];
    const float* bj2    = (const float*)d_in[16];

    float* out = (float*)d_out;
    float* logits_out   = out;
    float* out_lens_out = out + (size_t)BB * TT * E_DIM;
    float* labels_out   = out_lens_out + BB;
    float* counts_out   = labels_out + (size_t)BB * LBUF;

    float* ws    = (float*)d_ws;
    float* Fproj = ws + OFF_FPROJ;
    float* WjhR  = ws + OFF_WJHR;
    float* EP    = ws + OFF_EP;
    float* b1    = ws + OFF_B1;
    float* MA    = ws + OFF_MA;
    float* MB    = ws + OFF_MB;
    float* PL    = ws + OFF_PL;
    int*   syncw = (int*)(ws + OFF_SYNC);

    // dynamic LDS: 64 rows * LPITCH floats = 82,944 B (> 64 KB default cap)
    const int dynBytes = 64 * LPITCH * 4;
    hipFuncSetAttribute((const void*)decode_persistent,
                        hipFuncAttributeMaxDynamicSharedMemorySize, dynBytes);

    {
        int total = 163840 + G4;
        prep_t_kernel<<<(total + 255) / 256, 256, 0, stream>>>(Wj1, bih1, bhh1, WjhR, b1);
    }
    ep_kernel<<<VV, 256, 0, stream>>>(embed, Wih0, bih0, bhh0, EP);
    enc_fproj_kernel<<<(BB * TT) / 8, 512, 0, stream>>>(x, Wenc, benc, Wj1, bj1,
                                                        logits_out, Fproj);
    init_kernel<<<1, 1024, 0, stream>>>(lens, ws, out_lens_out, labels_out);
    decode_persistent<<<NB, 1024, dynBytes, stream>>>(lens, Fproj, Whh0, Wih1, Whh1,
                                                      WjhR, Wj2, EP, b1, bj2,
                                                      MA, MB, PL, syncw,
                                                      labels_out, counts_out);
}